// Round 1
// baseline (199.729 us; speedup 1.0000x reference)
//
#include <hip/hip_runtime.h>
#include <hip/hip_bf16.h>

// Graph attention: B=8,H=8,N=1024,d=128. fp32 in/out, bf16 MFMA compute.
// R10: software-pipelined attn_fast (T3/T4-lite + T5 on top of R9):
//  - K tiles double-buffered in LDS; K[kt+1] issued at top of iter kt
//    (covered by S-phase + softmax + PV, ~a full iteration of latency hiding).
//  - V single-buffered; V[kt] issued right after barrier A, consumed at PV
//    (covered by S-phase + softmax).
//  - Raw s_barrier + counted s_waitcnt instead of __syncthreads:
//      barrier A: vmcnt(0)  (only K[kt] in flight -> free, unconditionally safe)
//      barrier B: vmcnt(4)  (retires V[kt], keeps K[kt+1]'s 4 loads in flight)
//    VMEM issue order pinned adj(32) -> V(4) -> K'(4) via sched_barrier(0)
//    so the counted waits stay correct.
//  - s_setprio(1) around both MFMA clusters (T5).
// LDS: 32K (K dbuf) + 16K (V) + 18K (Ps) = 66.5 KB -> still 2 blocks/CU.
// Falls back to the R8 kernel if ws_size < 33.6 MB.

typedef __bf16 bf16x8 __attribute__((ext_vector_type(8)));
typedef float  f32x4  __attribute__((ext_vector_type(4)));
typedef unsigned int u32;

#define NSEQ 1024
#define DH   128
#define BN   64
#define NKT  16
#define TILE_ELEMS (BN * DH)           // 8192 bf16 = 16 KB
#define C1 0.1803368801111244f         // 0.125 * log2(e)
#define C2 11.5415603271110070f        // 8 * log2(e)

__device__ __forceinline__ float f4get(const float4& v, int c) {
    return (c == 0) ? v.x : (c == 1) ? v.y : (c == 2) ? v.z : v.w;
}

__device__ __forceinline__ void gload_lds16(const void* g, void* l) {
    __builtin_amdgcn_global_load_lds(
        (const __attribute__((address_space(1))) u32*)g,
        (__attribute__((address_space(3))) u32*)l, 16, 0, 0);
}

// ---------------- pre-pass: fp32 K/V -> swizzled bf16 tiles in ws ----------
__global__ __launch_bounds__(256)
void prepack_kernel(const float* __restrict__ K, const float* __restrict__ V,
                    __bf16* __restrict__ Kws, __bf16* __restrict__ Vws)
{
    const int tid = threadIdx.x;
    const int id  = blockIdx.x;            // 64 bh x 16 kt
    const size_t gbase = (size_t)(id >> 4) * NSEQ * DH + (size_t)(id & 15) * BN * DH;
    __bf16* ko = Kws + (size_t)id * TILE_ELEMS;
    __bf16* vo = Vws + (size_t)id * TILE_ELEMS;

    // K tile 64x128: row r, 16 chunks of 8 elems; swizzle low3: c^(r&7)
    {
        const int r  = tid >> 2;
        const int c0 = (tid & 3) * 4;
        #pragma unroll
        for (int cc = 0; cc < 4; ++cc) {
            const int c = c0 + cc;
            const float* src = K + gbase + (size_t)r * DH + c * 8;
            float4 a = *(const float4*)src;
            float4 b = *(const float4*)(src + 4);
            bf16x8 w;
            w[0]=(__bf16)a.x; w[1]=(__bf16)a.y; w[2]=(__bf16)a.z; w[3]=(__bf16)a.w;
            w[4]=(__bf16)b.x; w[5]=(__bf16)b.y; w[6]=(__bf16)b.z; w[7]=(__bf16)b.w;
            const int cs = (c & 8) | ((c ^ (r & 7)) & 7);
            *(bf16x8*)(ko + r * DH + cs * 8) = w;
        }
    }
    // V tile transposed -> [d][kv] 128x64: row d, 8 chunks of 8 kv; swz c^(d&7)
    {
        const int vkvb = tid >> 5;         // 0..7
        const int vdb  = tid & 31;         // 4 d each
        float4 vr[8];
        #pragma unroll
        for (int rr = 0; rr < 8; ++rr)
            vr[rr] = *(const float4*)(V + gbase + (size_t)(vkvb * 8 + rr) * DH + vdb * 4);
        #pragma unroll
        for (int c = 0; c < 4; ++c) {
            const int d = vdb * 4 + c;
            bf16x8 w;
            #pragma unroll
            for (int j = 0; j < 8; ++j) w[j] = (__bf16)f4get(vr[j], c);
            const int cs = vkvb ^ (d & 7);
            *(bf16x8*)(vo + d * BN + cs * 8) = w;
        }
    }
}

// ---------------- hot kernel: pipelined flash attention --------------------
__global__ __launch_bounds__(256, 2)
void attn_fast(const float* __restrict__ Q, const __bf16* __restrict__ Kws,
               const __bf16* __restrict__ Vws, const int* __restrict__ adj,
               float* __restrict__ out)
{
    __shared__ __attribute__((aligned(16))) __bf16 Kt[2][TILE_ELEMS]; // 32 KB dbuf
    __shared__ __attribute__((aligned(16))) __bf16 Vt[TILE_ELEMS];    // 16 KB
    __shared__ __attribute__((aligned(16))) __bf16 Ps[128 * 72];      // 18 KB

    const int tid  = threadIdx.x;
    const int wave = tid >> 6;            // 0..3, owns q-rows wave*32..+31
    const int lane = tid & 63;
    const int n16  = lane & 15;
    const int quad = lane >> 4;
    const int m7   = n16 & 7;

    const int id = blockIdx.x;            // XCD swizzle (R6-proven)
    const int bh = (id & 7) * 8 + ((id >> 3) & 7);
    const int q0 = (id >> 6) * 128;
    const size_t base  = (size_t)bh * NSEQ * DH;
    const size_t tile0 = (size_t)(bh * NKT) * TILE_ELEMS;

    // Q fragments (fp32 global, one-time), 2 row-tiles
    bf16x8 qf[2][4];
    #pragma unroll
    for (int rt = 0; rt < 2; ++rt)
        #pragma unroll
        for (int ks = 0; ks < 4; ++ks) {
            const float* src = Q + base + (size_t)(q0 + wave * 32 + rt * 16 + n16) * DH
                             + ks * 32 + quad * 8;
            float4 a = *(const float4*)src;
            float4 b = *(const float4*)(src + 4);
            bf16x8 w;
            w[0]=(__bf16)a.x; w[1]=(__bf16)a.y; w[2]=(__bf16)a.z; w[3]=(__bf16)a.w;
            w[4]=(__bf16)b.x; w[5]=(__bf16)b.y; w[6]=(__bf16)b.z; w[7]=(__bf16)b.w;
            qf[rt][ks] = w;
        }

    f32x4 o[2][8];
    #pragma unroll
    for (int rt = 0; rt < 2; ++rt)
        #pragma unroll
        for (int i = 0; i < 8; ++i) o[rt][i] = (f32x4){0.f, 0.f, 0.f, 0.f};
    float lp[2][4] = {{0.f,0.f,0.f,0.f},{0.f,0.f,0.f,0.f}};

    // ---- prologue: stage K[0] into Kt[0] ----
    #pragma unroll
    for (int j = 0; j < 4; ++j) {
        const int off = wave * 2048 + j * 512;
        gload_lds16(Kws + tile0 + off + lane * 8, &Kt[0][off]);
    }

    for (int kt = 0; kt < NKT; ++kt) {
        const int kv0 = kt * BN;

        // ---- barrier A: own K[kt] loads retired (only thing in flight),
        //      then join -> all waves' K[kt] stores visible; all waves past
        //      PV[kt-1] so Vt and Kt[(kt+1)&1] are free to overwrite.
        __builtin_amdgcn_sched_barrier(0);
        asm volatile("s_waitcnt vmcnt(0)" ::: "memory");
        __builtin_amdgcn_sched_barrier(0);
        __builtin_amdgcn_s_barrier();
        __builtin_amdgcn_sched_barrier(0);

        // ---- adj loads FIRST in VMEM order (retire before V/K' in the
        //      compiler's auto-inserted wait; latency hidden under S-phase)
        int am[2][4][4];
        #pragma unroll
        for (int rt = 0; rt < 2; ++rt)
            #pragma unroll
            for (int i = 0; i < 4; ++i)
                #pragma unroll
                for (int t = 0; t < 4; ++t)
                    am[rt][i][t] = adj[(size_t)(q0 + wave * 32 + rt * 16 + quad * 4 + i) * NSEQ
                                       + kv0 + t * 16 + n16];
        __builtin_amdgcn_sched_barrier(0);

        // ---- stage V[kt] (next 4 VMEM ops; hidden under S + softmax) ----
        {
            const __bf16* vtile = Vws + tile0 + (size_t)kt * TILE_ELEMS;
            #pragma unroll
            for (int j = 0; j < 4; ++j) {
                const int off = wave * 2048 + j * 512;
                gload_lds16(vtile + off + lane * 8, &Vt[off]);
            }
        }
        __builtin_amdgcn_sched_barrier(0);

        // ---- prefetch K[kt+1] (last 4 VMEM ops; stays in flight across
        //      barrier B, retired at next iter's barrier A) ----
        {
            const int ktn = (kt + 1) & (NKT - 1);   // last iter: dead write to buf 0
            const __bf16* ktile = Kws + tile0 + (size_t)ktn * TILE_ELEMS;
            __bf16* kdst = &Kt[ktn & 1][0];
            #pragma unroll
            for (int j = 0; j < 4; ++j) {
                const int off = wave * 2048 + j * 512;
                gload_lds16(ktile + off + lane * 8, kdst + off);
            }
        }
        __builtin_amdgcn_sched_barrier(0);

        // ---- S = Q K^T : 32 rows x 64 cols; swizzled Kt reads ----
        const __bf16* Kc = &Kt[kt & 1][0];
        float sc[2][4][4];
        __builtin_amdgcn_s_setprio(1);
        #pragma unroll
        for (int t = 0; t < 4; ++t) {
            f32x4 acc0 = (f32x4){0.f, 0.f, 0.f, 0.f};
            f32x4 acc1 = (f32x4){0.f, 0.f, 0.f, 0.f};
            #pragma unroll
            for (int ks = 0; ks < 4; ++ks) {
                const int c  = ks * 4 + quad;
                const int cs = (c & 8) | ((c ^ m7) & 7);
                bf16x8 bfr = *(const bf16x8*)(Kc + (t * 16 + n16) * DH + cs * 8);
                acc0 = __builtin_amdgcn_mfma_f32_16x16x32_bf16(qf[0][ks], bfr, acc0, 0, 0, 0);
                acc1 = __builtin_amdgcn_mfma_f32_16x16x32_bf16(qf[1][ks], bfr, acc1, 0, 0, 0);
            }
            #pragma unroll
            for (int i = 0; i < 4; ++i) { sc[0][t][i] = acc0[i]; sc[1][t][i] = acc1[i]; }
        }
        __builtin_amdgcn_s_setprio(0);

        // ---- fixed-shift masked softmax; P into wave-private rows ----
        #pragma unroll
        for (int rt = 0; rt < 2; ++rt)
            #pragma unroll
            for (int i = 0; i < 4; ++i) {
                const int prow = wave * 32 + rt * 16 + quad * 4 + i;
                float rowsum = 0.f;
                #pragma unroll
                for (int t = 0; t < 4; ++t) {
                    float p = exp2f(sc[rt][t][i] * C1 - C2);
                    p = (am[rt][i][t] > 0) ? p : 0.f;
                    rowsum += p;
                    Ps[prow * 72 + t * 16 + n16] = (__bf16)p;
                }
                lp[rt][i] += rowsum;
            }

        // ---- barrier B: retire V[kt] (keep K[kt+1] in flight), Ps drained ----
        __builtin_amdgcn_sched_barrier(0);
        asm volatile("s_waitcnt vmcnt(4) lgkmcnt(0)" ::: "memory");
        __builtin_amdgcn_sched_barrier(0);
        __builtin_amdgcn_s_barrier();
        __builtin_amdgcn_sched_barrier(0);

        // ---- O += P V (P rows wave-private; Vt stable since barrier B) ----
        __builtin_amdgcn_s_setprio(1);
        #pragma unroll
        for (int ks = 0; ks < 2; ++ks) {
            bf16x8 pf0 = *(const bf16x8*)(&Ps[(wave * 32 + n16)      * 72 + ks * 32 + quad * 8]);
            bf16x8 pf1 = *(const bf16x8*)(&Ps[(wave * 32 + 16 + n16) * 72 + ks * 32 + quad * 8]);
            #pragma unroll
            for (int nt = 0; nt < 8; ++nt) {
                const int d  = nt * 16 + n16;
                const int cs = (ks * 4 + quad) ^ m7;   // d&7 == n16&7
                bf16x8 vf = *(const bf16x8*)(&Vt[d * BN + cs * 8]);
                o[0][nt] = __builtin_amdgcn_mfma_f32_16x16x32_bf16(pf0, vf, o[0][nt], 0, 0, 0);
                o[1][nt] = __builtin_amdgcn_mfma_f32_16x16x32_bf16(pf1, vf, o[1][nt], 0, 0, 0);
            }
        }
        __builtin_amdgcn_s_setprio(0);
    }

    // ---- epilogue ----
    #pragma unroll
    for (int rt = 0; rt < 2; ++rt) {
        float linv[4];
        #pragma unroll
        for (int i = 0; i < 4; ++i) {
            float ls = lp[rt][i];
            ls += __shfl_xor(ls, 1);
            ls += __shfl_xor(ls, 2);
            ls += __shfl_xor(ls, 4);
            ls += __shfl_xor(ls, 8);
            linv[i] = 1.0f / fmaxf(ls, 1e-30f);
        }
        const int qrow = q0 + wave * 32 + rt * 16 + quad * 4;
        #pragma unroll
        for (int nt = 0; nt < 8; ++nt)
            #pragma unroll
            for (int i = 0; i < 4; ++i)
                out[base + (size_t)(qrow + i) * DH + nt * 16 + n16] = o[rt][nt][i] * linv[i];
    }
}

// ---------------- fallback (R8-proven) if ws too small ----------------------
#define KS_STRIDE 136
#define VT_STRIDE 64
#define PS_STRIDE 72

__global__ __launch_bounds__(256, 4)
void attn_fallback(const float* __restrict__ Q, const float* __restrict__ K,
                   const float* __restrict__ V, const int* __restrict__ adj,
                   float* __restrict__ out)
{
    __shared__ __attribute__((aligned(16))) __bf16 KsP[BN * KS_STRIDE];
    __shared__ __attribute__((aligned(16))) __bf16 Vts[DH * VT_STRIDE];
    const int tid = threadIdx.x;
    const int wave = tid >> 6, lane = tid & 63, n16 = lane & 15, quad = lane >> 4;
    const int id = blockIdx.x;
    const int bh = (id & 7) * 8 + ((id >> 3) & 7);
    const int q0 = (id >> 6) * 64;
    const size_t base = (size_t)bh * NSEQ * DH;
    const int rp = tid >> 4, kcol = (tid & 15) * 8, db = tid & 31, kvb = tid >> 5;
    bf16x8 qf[4];
    #pragma unroll
    for (int ks = 0; ks < 4; ++ks) {
        const float* src = Q + base + (size_t)(q0 + wave * 16 + n16) * DH + ks * 32 + quad * 8;
        float4 a = *(const float4*)src; float4 b = *(const float4*)(src + 4);
        bf16x8 w;
        w[0]=(__bf16)a.x; w[1]=(__bf16)a.y; w[2]=(__bf16)a.z; w[3]=(__bf16)a.w;
        w[4]=(__bf16)b.x; w[5]=(__bf16)b.y; w[6]=(__bf16)b.z; w[7]=(__bf16)b.w;
        qf[ks] = w;
    }
    f32x4 o[8];
    #pragma unroll
    for (int i = 0; i < 8; ++i) o[i] = (f32x4){0.f, 0.f, 0.f, 0.f};
    float lp[4] = {0.f, 0.f, 0.f, 0.f};
    const int qrow = q0 + wave * 16 + quad * 4;
    for (int kt = 0; kt < NKT; ++kt) {
        const int kv0 = kt * BN;
        __syncthreads();
        #pragma unroll
        for (int it = 0; it < 4; ++it) {
            int row = 16 * it + rp;
            const float* src = K + base + (size_t)(kv0 + row) * DH + kcol;
            float4 a = *(const float4*)src; float4 b = *(const float4*)(src + 4);
            bf16x8 w;
            w[0]=(__bf16)a.x; w[1]=(__bf16)a.y; w[2]=(__bf16)a.z; w[3]=(__bf16)a.w;
            w[4]=(__bf16)b.x; w[5]=(__bf16)b.y; w[6]=(__bf16)b.z; w[7]=(__bf16)b.w;
            *(bf16x8*)(&KsP[row * KS_STRIDE + kcol]) = w;
        }
        {
            float4 vreg[8];
            #pragma unroll
            for (int rr = 0; rr < 8; ++rr)
                vreg[rr] = *(const float4*)(V + base + (size_t)(kv0 + kvb * 8 + rr) * DH + db * 4);
            #pragma unroll
            for (int c = 0; c < 4; ++c) {
                bf16x8 w;
                #pragma unroll
                for (int j = 0; j < 8; ++j) w[j] = (__bf16)f4get(vreg[j], c);
                int d = db * 4 + c, s = (d ^ (d >> 3)) & 7;
                *(bf16x8*)(&Vts[d * VT_STRIDE + ((kvb ^ s) << 3)]) = w;
            }
        }
        __syncthreads();
        int am[4][4];
        #pragma unroll
        for (int i = 0; i < 4; ++i)
            #pragma unroll
            for (int t = 0; t < 4; ++t)
                am[i][t] = adj[(size_t)(qrow + i) * NSEQ + kv0 + t * 16 + n16];
        float sc[4][4];
        #pragma unroll
        for (int t = 0; t < 4; ++t) {
            f32x4 acc = (f32x4){0.f, 0.f, 0.f, 0.f};
            #pragma unroll
            for (int ks = 0; ks < 4; ++ks) {
                bf16x8 bfr = *(const bf16x8*)(&KsP[(t * 16 + n16) * KS_STRIDE + ks * 32 + quad * 8]);
                acc = __builtin_amdgcn_mfma_f32_16x16x32_bf16(qf[ks], bfr, acc, 0, 0, 0);
            }
            #pragma unroll
            for (int i = 0; i < 4; ++i) sc[t][i] = acc[i];
        }
        __syncthreads();
        #pragma unroll
        for (int i = 0; i < 4; ++i) {
            const int prow = wave * 16 + quad * 4 + i;
            float rowsum = 0.f;
            #pragma unroll
            for (int t = 0; t < 4; ++t) {
                float p = exp2f(sc[t][i] * C1 - C2);
                p = (am[i][t] > 0) ? p : 0.f;
                rowsum += p;
                KsP[prow * PS_STRIDE + t * 16 + n16] = (__bf16)p;
            }
            lp[i] += rowsum;
        }
        #pragma unroll
        for (int ks = 0; ks < 2; ++ks) {
            bf16x8 pf = *(const bf16x8*)(&KsP[(wave * 16 + n16) * PS_STRIDE + ks * 32 + quad * 8]);
            #pragma unroll
            for (int nt = 0; nt < 8; ++nt) {
                int d = nt * 16 + n16, s = (d ^ (d >> 3)) & 7, kvbr = ks * 4 + quad;
                bf16x8 vf = *(const bf16x8*)(&Vts[d * VT_STRIDE + ((kvbr ^ s) << 3)]);
                o[nt] = __builtin_amdgcn_mfma_f32_16x16x32_bf16(pf, vf, o[nt], 0, 0, 0);
            }
        }
    }
    float linv[4];
    #pragma unroll
    for (int i = 0; i < 4; ++i) {
        float ls = lp[i];
        ls += __shfl_xor(ls, 1); ls += __shfl_xor(ls, 2);
        ls += __shfl_xor(ls, 4); ls += __shfl_xor(ls, 8);
        linv[i] = 1.0f / fmaxf(ls, 1e-30f);
    }
    #pragma unroll
    for (int nt = 0; nt < 8; ++nt)
        #pragma unroll
        for (int i = 0; i < 4; ++i)
            out[base + (size_t)(qrow + i) * DH + nt * 16 + n16] = o[nt][i] * linv[i];
}

extern "C" void kernel_launch(void* const* d_in, const int* in_sizes, int n_in,
                              void* d_out, int out_size, void* d_ws, size_t ws_size,
                              hipStream_t stream) {
    const float* Q   = (const float*)d_in[0];
    const float* K   = (const float*)d_in[1];
    const float* V   = (const float*)d_in[2];
    const int*   adj = (const int*)d_in[3];
    float* out = (float*)d_out;
    const size_t need = (size_t)2 * 64 * NKT * TILE_ELEMS * sizeof(__bf16); // 33.6 MB
    if (ws_size >= need) {
        __bf16* Kws = (__bf16*)d_ws;
        __bf16* Vws = Kws + (size_t)64 * NKT * TILE_ELEMS;
        prepack_kernel<<<1024, 256, 0, stream>>>(K, V, Kws, Vws);
        attn_fast<<<512, 256, 0, stream>>>(Q, Kws, Vws, adj, out);
    } else {
        attn_fallback<<<1024, 256, 0, stream>>>(Q, K, V, adj, out);
    }
}

// Round 2
// 195.905 us; speedup vs baseline: 1.0195x; 1.0195x over previous
//
#include <hip/hip_runtime.h>
#include <hip/hip_bf16.h>

// Graph attention: B=8,H=8,N=1024,d=128. fp32 in/out, bf16 MFMA compute.
// R11: occupancy + adj-bitmask rework on top of R10:
//  - attn_fast now 512 threads (8 waves x 16 q-rows), grid 512 -> 2 blocks/CU
//    = 16 waves/CU = 4 waves/SIMD (was 2). Same BM=128, same LDS (66.5 KB).
//  - adjacency pre-packed to bitmasks in ws: adjp[row][c] = u64, bit b =
//    adj[row][16*b+c] > 0. Each thread loads 4 u64 ONCE before the loop;
//    per-iter mask = (aw >> 4kt) & 0xF. Removes ALL adj loads + address math
//    from the hot loop (was 512 scalar loads/thread).
//  - K dbuf + counted-vmcnt pipeline kept (R10): barrier A vmcnt(0),
//    barrier B vmcnt(2) keeps K[kt+1]'s 2 loads in flight. setprio on MFMA.
// Falls back to the R8 kernel if ws too small.

typedef __bf16 bf16x8 __attribute__((ext_vector_type(8)));
typedef float  f32x4  __attribute__((ext_vector_type(4)));
typedef unsigned int u32;
typedef unsigned long long u64;

#define NSEQ 1024
#define DH   128
#define BN   64
#define NKT  16
#define TILE_ELEMS (BN * DH)           // 8192 bf16 = 16 KB
#define C1 0.1803368801111244f         // 0.125 * log2(e)
#define C2 11.5415603271110070f        // 8 * log2(e)

__device__ __forceinline__ float f4get(const float4& v, int c) {
    return (c == 0) ? v.x : (c == 1) ? v.y : (c == 2) ? v.z : v.w;
}

__device__ __forceinline__ void gload_lds16(const void* g, void* l) {
    __builtin_amdgcn_global_load_lds(
        (const __attribute__((address_space(1))) u32*)g,
        (__attribute__((address_space(3))) u32*)l, 16, 0, 0);
}

// ---------------- pre-pass: fp32 K/V -> swizzled bf16 tiles; adj -> bits ----
__global__ __launch_bounds__(256)
void prepack_kernel(const float* __restrict__ K, const float* __restrict__ V,
                    __bf16* __restrict__ Kws, __bf16* __restrict__ Vws,
                    u64* __restrict__ adjp, const int* __restrict__ adj)
{
    const int tid = threadIdx.x;
    const int id  = blockIdx.x;

    if (id >= 1024) {
        // adj bit-pack: 64 blocks, each 16 rows x 16 classes.
        // adjp[r*16+c] bit b = adj[r][16*b+c] > 0   (b = kt*4+t in the consumer)
        const int r = (id - 1024) * 16 + (tid >> 4);
        const int c = tid & 15;
        const int* row = adj + (size_t)r * NSEQ + c;
        u64 w = 0;
        #pragma unroll
        for (int j = 0; j < 64; ++j)
            w |= (u64)(row[j * 16] > 0) << j;
        adjp[(size_t)r * 16 + c] = w;
        return;
    }

    const size_t gbase = (size_t)(id >> 4) * NSEQ * DH + (size_t)(id & 15) * BN * DH;
    __bf16* ko = Kws + (size_t)id * TILE_ELEMS;
    __bf16* vo = Vws + (size_t)id * TILE_ELEMS;

    // K tile 64x128: row r, 16 chunks of 8 elems; swizzle low3: c^(r&7)
    {
        const int r  = tid >> 2;
        const int c0 = (tid & 3) * 4;
        #pragma unroll
        for (int cc = 0; cc < 4; ++cc) {
            const int c = c0 + cc;
            const float* src = K + gbase + (size_t)r * DH + c * 8;
            float4 a = *(const float4*)src;
            float4 b = *(const float4*)(src + 4);
            bf16x8 w;
            w[0]=(__bf16)a.x; w[1]=(__bf16)a.y; w[2]=(__bf16)a.z; w[3]=(__bf16)a.w;
            w[4]=(__bf16)b.x; w[5]=(__bf16)b.y; w[6]=(__bf16)b.z; w[7]=(__bf16)b.w;
            const int cs = (c & 8) | ((c ^ (r & 7)) & 7);
            *(bf16x8*)(ko + r * DH + cs * 8) = w;
        }
    }
    // V tile transposed -> [d][kv] 128x64: row d, 8 chunks of 8 kv; swz c^(d&7)
    {
        const int vkvb = tid >> 5;         // 0..7
        const int vdb  = tid & 31;         // 4 d each
        float4 vr[8];
        #pragma unroll
        for (int rr = 0; rr < 8; ++rr)
            vr[rr] = *(const float4*)(V + gbase + (size_t)(vkvb * 8 + rr) * DH + vdb * 4);
        #pragma unroll
        for (int c = 0; c < 4; ++c) {
            const int d = vdb * 4 + c;
            bf16x8 w;
            #pragma unroll
            for (int j = 0; j < 8; ++j) w[j] = (__bf16)f4get(vr[j], c);
            const int cs = vkvb ^ (d & 7);
            *(bf16x8*)(vo + d * BN + cs * 8) = w;
        }
    }
}

// ---------------- hot kernel: 8-wave pipelined flash attention --------------
__global__ __launch_bounds__(512, 4)
void attn_fast(const float* __restrict__ Q, const __bf16* __restrict__ Kws,
               const __bf16* __restrict__ Vws, const u64* __restrict__ adjp,
               float* __restrict__ out)
{
    __shared__ __attribute__((aligned(16))) __bf16 Kt[2][TILE_ELEMS]; // 32 KB dbuf
    __shared__ __attribute__((aligned(16))) __bf16 Vt[TILE_ELEMS];    // 16 KB
    __shared__ __attribute__((aligned(16))) __bf16 Ps[128 * 72];      // 18 KB

    const int tid  = threadIdx.x;
    const int wave = tid >> 6;            // 0..7, owns q-rows wave*16..+15
    const int lane = tid & 63;
    const int n16  = lane & 15;
    const int quad = lane >> 4;
    const int m7   = n16 & 7;

    const int id = blockIdx.x;            // XCD swizzle (R6-proven)
    const int bh = (id & 7) * 8 + ((id >> 3) & 7);
    const int q0 = (id >> 6) * 128;
    const size_t base  = (size_t)bh * NSEQ * DH;
    const size_t tile0 = (size_t)(bh * NKT) * TILE_ELEMS;
    const int qrb = q0 + wave * 16 + quad * 4;   // this thread's 4 output rows

    // Q fragments (fp32 global, one-time)
    bf16x8 qf[4];
    #pragma unroll
    for (int ks = 0; ks < 4; ++ks) {
        const float* src = Q + base + (size_t)(q0 + wave * 16 + n16) * DH
                         + ks * 32 + quad * 8;
        float4 a = *(const float4*)src;
        float4 b = *(const float4*)(src + 4);
        bf16x8 w;
        w[0]=(__bf16)a.x; w[1]=(__bf16)a.y; w[2]=(__bf16)a.z; w[3]=(__bf16)a.w;
        w[4]=(__bf16)b.x; w[5]=(__bf16)b.y; w[6]=(__bf16)b.z; w[7]=(__bf16)b.w;
        qf[ks] = w;
    }

    // adjacency bitmasks: one u64 per owned row, covers ALL 16 kv-tiles
    u64 aw[4];
    #pragma unroll
    for (int i = 0; i < 4; ++i)
        aw[i] = adjp[(size_t)(qrb + i) * 16 + n16];

    f32x4 o[8];
    #pragma unroll
    for (int i = 0; i < 8; ++i) o[i] = (f32x4){0.f, 0.f, 0.f, 0.f};
    float lp[4] = {0.f, 0.f, 0.f, 0.f};

    // ---- prologue: stage K[0] into Kt[0] (2 insts/wave, 1 KB each) ----
    #pragma unroll
    for (int j = 0; j < 2; ++j) {
        const int off = wave * 1024 + j * 512;
        gload_lds16(Kws + tile0 + off + lane * 8, &Kt[0][off]);
    }

    for (int kt = 0; kt < NKT; ++kt) {
        // ---- barrier A: own K[kt] loads (only VMEM in flight) retired,
        //      then join -> Kt[kt&1] visible; all waves past PV[kt-1] so
        //      Vt and Kt[(kt+1)&1] are free to overwrite.
        __builtin_amdgcn_sched_barrier(0);
        asm volatile("s_waitcnt vmcnt(0)" ::: "memory");
        __builtin_amdgcn_sched_barrier(0);
        __builtin_amdgcn_s_barrier();
        __builtin_amdgcn_sched_barrier(0);

        // ---- stage V[kt] (first 2 VMEM ops; hidden under S + softmax) ----
        {
            const __bf16* vtile = Vws + tile0 + (size_t)kt * TILE_ELEMS;
            #pragma unroll
            for (int j = 0; j < 2; ++j) {
                const int off = wave * 1024 + j * 512;
                gload_lds16(vtile + off + lane * 8, &Vt[off]);
            }
        }
        __builtin_amdgcn_sched_barrier(0);

        // ---- prefetch K[kt+1] (last 2 VMEM ops; stays in flight across
        //      barrier B, retired at next iter's barrier A) ----
        {
            const int ktn = (kt + 1) & (NKT - 1);   // last iter: dead write
            const __bf16* ktile = Kws + tile0 + (size_t)ktn * TILE_ELEMS;
            __bf16* kdst = &Kt[ktn & 1][0];
            #pragma unroll
            for (int j = 0; j < 2; ++j) {
                const int off = wave * 1024 + j * 512;
                gload_lds16(ktile + off + lane * 8, kdst + off);
            }
        }
        __builtin_amdgcn_sched_barrier(0);

        // ---- S = Q K^T : 16 rows x 64 cols; swizzled Kt reads ----
        const __bf16* Kc = &Kt[kt & 1][0];
        float sc[4][4];
        __builtin_amdgcn_s_setprio(1);
        #pragma unroll
        for (int t = 0; t < 4; ++t) {
            f32x4 acc = (f32x4){0.f, 0.f, 0.f, 0.f};
            #pragma unroll
            for (int ks = 0; ks < 4; ++ks) {
                const int c  = ks * 4 + quad;
                const int cs = (c & 8) | ((c ^ m7) & 7);
                bf16x8 bfr = *(const bf16x8*)(Kc + (t * 16 + n16) * DH + cs * 8);
                acc = __builtin_amdgcn_mfma_f32_16x16x32_bf16(qf[ks], bfr, acc, 0, 0, 0);
            }
            #pragma unroll
            for (int i = 0; i < 4; ++i) sc[t][i] = acc[i];
        }
        __builtin_amdgcn_s_setprio(0);

        // ---- masked softmax from register bitmask; P into wave-private rows
        #pragma unroll
        for (int i = 0; i < 4; ++i) {
            const unsigned w4 = (unsigned)(aw[i] >> (kt * 4)) & 0xFu;
            const int prow = wave * 16 + quad * 4 + i;
            float rowsum = 0.f;
            #pragma unroll
            for (int t = 0; t < 4; ++t) {
                float p = exp2f(sc[t][i] * C1 - C2);
                p = (w4 & (1u << t)) ? p : 0.f;
                rowsum += p;
                Ps[prow * 72 + t * 16 + n16] = (__bf16)p;
            }
            lp[i] += rowsum;
        }

        // ---- barrier B: retire V[kt] (keep K[kt+1] in flight), Ps drained ----
        __builtin_amdgcn_sched_barrier(0);
        asm volatile("s_waitcnt vmcnt(2) lgkmcnt(0)" ::: "memory");
        __builtin_amdgcn_sched_barrier(0);
        __builtin_amdgcn_s_barrier();
        __builtin_amdgcn_sched_barrier(0);

        // ---- O += P V (P rows wave-private; Vt stable since barrier B) ----
        __builtin_amdgcn_s_setprio(1);
        #pragma unroll
        for (int ks = 0; ks < 2; ++ks) {
            bf16x8 pf = *(const bf16x8*)(&Ps[(wave * 16 + n16) * 72 + ks * 32 + quad * 8]);
            #pragma unroll
            for (int nt = 0; nt < 8; ++nt) {
                const int d  = nt * 16 + n16;
                const int cs = (ks * 4 + quad) ^ m7;   // d&7 == n16&7
                bf16x8 vf = *(const bf16x8*)(&Vt[d * BN + cs * 8]);
                o[nt] = __builtin_amdgcn_mfma_f32_16x16x32_bf16(pf, vf, o[nt], 0, 0, 0);
            }
        }
        __builtin_amdgcn_s_setprio(0);
    }

    // ---- epilogue ----
    float linv[4];
    #pragma unroll
    for (int i = 0; i < 4; ++i) {
        float ls = lp[i];
        ls += __shfl_xor(ls, 1);
        ls += __shfl_xor(ls, 2);
        ls += __shfl_xor(ls, 4);
        ls += __shfl_xor(ls, 8);
        linv[i] = 1.0f / fmaxf(ls, 1e-30f);
    }
    #pragma unroll
    for (int nt = 0; nt < 8; ++nt)
        #pragma unroll
        for (int i = 0; i < 4; ++i)
            out[base + (size_t)(qrb + i) * DH + nt * 16 + n16] = o[nt][i] * linv[i];
}

// ---------------- fallback (R8-proven) if ws too small ----------------------
#define KS_STRIDE 136
#define VT_STRIDE 64
#define PS_STRIDE 72

__global__ __launch_bounds__(256, 4)
void attn_fallback(const float* __restrict__ Q, const float* __restrict__ K,
                   const float* __restrict__ V, const int* __restrict__ adj,
                   float* __restrict__ out)
{
    __shared__ __attribute__((aligned(16))) __bf16 KsP[BN * KS_STRIDE];
    __shared__ __attribute__((aligned(16))) __bf16 Vts[DH * VT_STRIDE];
    const int tid = threadIdx.x;
    const int wave = tid >> 6, lane = tid & 63, n16 = lane & 15, quad = lane >> 4;
    const int id = blockIdx.x;
    const int bh = (id & 7) * 8 + ((id >> 3) & 7);
    const int q0 = (id >> 6) * 64;
    const size_t base = (size_t)bh * NSEQ * DH;
    const int rp = tid >> 4, kcol = (tid & 15) * 8, db = tid & 31, kvb = tid >> 5;
    bf16x8 qf[4];
    #pragma unroll
    for (int ks = 0; ks < 4; ++ks) {
        const float* src = Q + base + (size_t)(q0 + wave * 16 + n16) * DH + ks * 32 + quad * 8;
        float4 a = *(const float4*)src; float4 b = *(const float4*)(src + 4);
        bf16x8 w;
        w[0]=(__bf16)a.x; w[1]=(__bf16)a.y; w[2]=(__bf16)a.z; w[3]=(__bf16)a.w;
        w[4]=(__bf16)b.x; w[5]=(__bf16)b.y; w[6]=(__bf16)b.z; w[7]=(__bf16)b.w;
        qf[ks] = w;
    }
    f32x4 o[8];
    #pragma unroll
    for (int i = 0; i < 8; ++i) o[i] = (f32x4){0.f, 0.f, 0.f, 0.f};
    float lp[4] = {0.f, 0.f, 0.f, 0.f};
    const int qrow = q0 + wave * 16 + quad * 4;
    for (int kt = 0; kt < NKT; ++kt) {
        const int kv0 = kt * BN;
        __syncthreads();
        #pragma unroll
        for (int it = 0; it < 4; ++it) {
            int row = 16 * it + rp;
            const float* src = K + base + (size_t)(kv0 + row) * DH + kcol;
            float4 a = *(const float4*)src; float4 b = *(const float4*)(src + 4);
            bf16x8 w;
            w[0]=(__bf16)a.x; w[1]=(__bf16)a.y; w[2]=(__bf16)a.z; w[3]=(__bf16)a.w;
            w[4]=(__bf16)b.x; w[5]=(__bf16)b.y; w[6]=(__bf16)b.z; w[7]=(__bf16)b.w;
            *(bf16x8*)(&KsP[row * KS_STRIDE + kcol]) = w;
        }
        {
            float4 vreg[8];
            #pragma unroll
            for (int rr = 0; rr < 8; ++rr)
                vreg[rr] = *(const float4*)(V + base + (size_t)(kv0 + kvb * 8 + rr) * DH + db * 4);
            #pragma unroll
            for (int c = 0; c < 4; ++c) {
                bf16x8 w;
                #pragma unroll
                for (int j = 0; j < 8; ++j) w[j] = (__bf16)f4get(vreg[j], c);
                int d = db * 4 + c, s = (d ^ (d >> 3)) & 7;
                *(bf16x8*)(&Vts[d * VT_STRIDE + ((kvb ^ s) << 3)]) = w;
            }
        }
        __syncthreads();
        int am[4][4];
        #pragma unroll
        for (int i = 0; i < 4; ++i)
            #pragma unroll
            for (int t = 0; t < 4; ++t)
                am[i][t] = adj[(size_t)(qrow + i) * NSEQ + kv0 + t * 16 + n16];
        float sc[4][4];
        #pragma unroll
        for (int t = 0; t < 4; ++t) {
            f32x4 acc = (f32x4){0.f, 0.f, 0.f, 0.f};
            #pragma unroll
            for (int ks = 0; ks < 4; ++ks) {
                bf16x8 bfr = *(const bf16x8*)(&KsP[(t * 16 + n16) * KS_STRIDE + ks * 32 + quad * 8]);
                acc = __builtin_amdgcn_mfma_f32_16x16x32_bf16(qf[ks], bfr, acc, 0, 0, 0);
            }
            #pragma unroll
            for (int i = 0; i < 4; ++i) sc[t][i] = acc[i];
        }
        __syncthreads();
        #pragma unroll
        for (int i = 0; i < 4; ++i) {
            const int prow = wave * 16 + quad * 4 + i;
            float rowsum = 0.f;
            #pragma unroll
            for (int t = 0; t < 4; ++t) {
                float p = exp2f(sc[t][i] * C1 - C2);
                p = (am[i][t] > 0) ? p : 0.f;
                rowsum += p;
                KsP[prow * PS_STRIDE + t * 16 + n16] = (__bf16)p;
            }
            lp[i] += rowsum;
        }
        #pragma unroll
        for (int ks = 0; ks < 2; ++ks) {
            bf16x8 pf = *(const bf16x8*)(&KsP[(wave * 16 + n16) * PS_STRIDE + ks * 32 + quad * 8]);
            #pragma unroll
            for (int nt = 0; nt < 8; ++nt) {
                int d = nt * 16 + n16, s = (d ^ (d >> 3)) & 7, kvbr = ks * 4 + quad;
                bf16x8 vf = *(const bf16x8*)(&Vts[d * VT_STRIDE + ((kvbr ^ s) << 3)]);
                o[nt] = __builtin_amdgcn_mfma_f32_16x16x32_bf16(pf, vf, o[nt], 0, 0, 0);
            }
        }
    }
    float linv[4];
    #pragma unroll
    for (int i = 0; i < 4; ++i) {
        float ls = lp[i];
        ls += __shfl_xor(ls, 1); ls += __shfl_xor(ls, 2);
        ls += __shfl_xor(ls, 4); ls += __shfl_xor(ls, 8);
        linv[i] = 1.0f / fmaxf(ls, 1e-30f);
    }
    #pragma unroll
    for (int nt = 0; nt < 8; ++nt)
        #pragma unroll
        for (int i = 0; i < 4; ++i)
            out[base + (size_t)(qrow + i) * DH + nt * 16 + n16] = o[nt][i] * linv[i];
}

extern "C" void kernel_launch(void* const* d_in, const int* in_sizes, int n_in,
                              void* d_out, int out_size, void* d_ws, size_t ws_size,
                              hipStream_t stream) {
    const float* Q   = (const float*)d_in[0];
    const float* K   = (const float*)d_in[1];
    const float* V   = (const float*)d_in[2];
    const int*   adj = (const int*)d_in[3];
    float* out = (float*)d_out;
    const size_t needKV  = (size_t)2 * 64 * NKT * TILE_ELEMS * sizeof(__bf16); // 33.6 MB
    const size_t needAdj = (size_t)NSEQ * 16 * sizeof(u64);                    // 128 KB
    if (ws_size >= needKV + needAdj) {
        __bf16* Kws = (__bf16*)d_ws;
        __bf16* Vws = Kws + (size_t)64 * NKT * TILE_ELEMS;
        u64* adjp = (u64*)(Vws + (size_t)64 * NKT * TILE_ELEMS);
        prepack_kernel<<<1088, 256, 0, stream>>>(K, V, Kws, Vws, adjp, adj);
        attn_fast<<<512, 512, 0, stream>>>(Q, Kws, Vws, adjp, out);
    } else {
        attn_fallback<<<1024, 256, 0, stream>>>(Q, K, V, adj, out);
    }
}